// Round 13
// baseline (205.673 us; speedup 1.0000x reference)
//
#include <hip/hip_runtime.h>

#define NN 2048
#define DD 256
#define HH 4
#define PW 1280      // gemm1 output width: 256 msg0 | 256 msg1 | 768 gh
#define ECAP 128     // max total edges per (col,layer) staged in LDS
#define SCAP 32      // slots per row-group segment (mean 3.8, +14 sigma)
#define NG 8         // row groups of 256 rows

typedef unsigned short ushort_t;
typedef __attribute__((ext_vector_type(4))) unsigned short us4;
typedef __attribute__((ext_vector_type(8))) short s8;
typedef __attribute__((ext_vector_type(4))) float f4;

__device__ __forceinline__ ushort_t f2b(float f) {   // fp32 -> bf16 bits, RNE
    unsigned int u = __float_as_uint(f);
    return (ushort_t)((u + 0x7fffu + ((u >> 16) & 1u)) >> 16);
}
__device__ __forceinline__ float b2f(ushort_t b) {
    return __uint_as_float(((unsigned int)b) << 16);
}
__device__ __forceinline__ void gl_lds16(const void* g, void* l) {
    __builtin_amdgcn_global_load_lds(
        (const __attribute__((address_space(1))) void*)g,
        (__attribute__((address_space(3))) void*)l, 16, 0, 0);
}

// ---------------------------------------------------------------------------
// K1: block-range union of independent input-only work.
//  [0,2048)      edge_build v4: block = (16-col chunk, layer, row-group of
//                256 rows). 8 blocks/CU + 8 upfront float4 loads/thread fixes
//                the r12 latency x parallelism deficit (was 1 block/CU, MLP~2).
//                Segmented lists: 8 segments x 32 slots per (col,layer);
//                LDS counters only, no global atomics.
//  [2048,2560)   xb = bf16(x)           float4 -> ushort4
//  [2560,2880)   Wcatb = bf16([Wm0;Wm1;whh])
//  [2880,3264)   wihb = bf16(wih)
//  [3264,3392)   attn_proj: acur/anb (fp32 exact)
// ---------------------------------------------------------------------------
#define E_EB  2048
#define E_XC  2560
#define E_WC  2880
#define E_WI  3264
#define E_NB  3392

__global__ __launch_bounds__(256) void prep_kernel(
    const float* __restrict__ x,
    const float* __restrict__ adj0, const float* __restrict__ adj1,
    const float* __restrict__ w0, const float* __restrict__ w1,
    const float* __restrict__ Wm0, const float* __restrict__ Wm1,
    const float* __restrict__ whh, const float* __restrict__ wih,
    const float* __restrict__ Wa0, const float* __restrict__ Wa1,
    int* __restrict__ cntg, uint2* __restrict__ ejw,
    ushort_t* __restrict__ xb, ushort_t* __restrict__ Wcatb, ushort_t* __restrict__ wihb,
    float* __restrict__ acur, float* __restrict__ anb)
{
    __shared__ float sh[16][257];
    const int b = blockIdx.x, t = threadIdx.x;

    if (b < E_EB) {                        // ---- edge_build v4 ----
        const int c = b & 127, l = (b >> 7) & 1, g = b >> 8;
        const int i0 = c * 16, j0 = g * 256;
        const float* adj = l ? adj1 : adj0;
        const float* w   = l ? w1 : w0;
        int* lcnt = (int*)sh;              // 16 LDS counters
        if (t < 16) lcnt[t] = 0;
        __syncthreads();
        const int rowLane = t >> 2, q = t & 3;
        float4 a[4], qw[4];
        #pragma unroll
        for (int it = 0; it < 4; ++it) {   // 8 loads in flight per thread
            const int j = j0 + it * 64 + rowLane;
            a[it]  = *(const float4*)(adj + (size_t)j * NN + i0 + q * 4);
            qw[it] = *(const float4*)(w   + (size_t)j * NN + i0 + q * 4);
        }
        #pragma unroll
        for (int it = 0; it < 4; ++it) {
            const int j = j0 + it * 64 + rowLane;
            const float av[4] = {a[it].x, a[it].y, a[it].z, a[it].w};
            const float qv[4] = {qw[it].x, qw[it].y, qw[it].z, qw[it].w};
            #pragma unroll
            for (int u = 0; u < 4; ++u) {
                if (av[u] != 0.f) {
                    const int li = q * 4 + u;
                    const int slot = atomicAdd(&lcnt[li], 1);
                    if (slot < SCAP) {
                        uint2 pk;
                        pk.x = (unsigned int)j;
                        pk.y = __float_as_uint(qv[u]);
                        ejw[(((size_t)l * NN + i0 + li) * NG + g) * SCAP + slot] = pk;
                    }
                }
            }
        }
        __syncthreads();
        if (t < 16)
            cntg[((size_t)l * NN + i0 + t) * NG + g] = min(lcnt[t], SCAP);
        return;
    }
    if (b < E_XC) {                        // ---- x -> bf16 ----
        const int id = (b - E_EB) * 1024 + t * 4;
        const float4 v = *(const float4*)(x + id);
        us4 o; o.x = f2b(v.x); o.y = f2b(v.y); o.z = f2b(v.z); o.w = f2b(v.w);
        *(us4*)(xb + id) = o;
        return;
    }
    if (b < E_WC) {                        // ---- [Wm0;Wm1;whh] -> bf16 ----
        const int id = (b - E_XC) * 1024 + t * 4;
        const int c = id >> 8, k = id & 255;
        const float* src = (c < 256) ? Wm0 + (size_t)c * DD + k
                         : (c < 512) ? Wm1 + (size_t)(c - 256) * DD + k
                                     : whh + (size_t)(c - 512) * DD + k;
        const float4 v = *(const float4*)src;
        us4 o; o.x = f2b(v.x); o.y = f2b(v.y); o.z = f2b(v.z); o.w = f2b(v.w);
        *(us4*)(Wcatb + id) = o;
        return;
    }
    if (b < E_WI) {                        // ---- wih -> bf16 ----
        const int id = (b - E_WC) * 1024 + t * 4;
        const float4 v = *(const float4*)(wih + id);
        us4 o; o.x = f2b(v.x); o.y = f2b(v.y); o.z = f2b(v.z); o.w = f2b(v.w);
        *(us4*)(wihb + id) = o;
        return;
    }
    {                                      // ---- attn_proj ----
        const int i0 = (b - E_WI) * 16;
        for (int rr = 0; rr < 16; ++rr)
            sh[rr][t] = x[(size_t)(i0 + rr) * DD + t];
        __syncthreads();
        const int r = t >> 4, idx = t & 15;
        const int l = idx >> 3, isnb = (idx >> 2) & 1, h = idx & 3;
        const float* wrow = (l ? Wa1 : Wa0) + h * (2 * DD) + isnb * DD;
        float acc = 0.f;
        for (int k = 0; k < DD; ++k) acc = fmaf(sh[r][k], wrow[k], acc);
        float* dst = isnb ? anb : acur;
        dst[((size_t)l * NN + i0 + r) * HH + h] = acc;
    }
}

// ---------------------------------------------------------------------------
// K2: gemm1: [msg0|msg1|gh] = x @ [Wm0;Wm1;whh]^T + bias. 64x64 tiles,
// 4 waves of 2x2 mfma_f32_16x16x32_bf16. global_load_lds 16B staging into
// unpadded [64][64] with XOR chunk swizzle.
// ---------------------------------------------------------------------------
__device__ __forceinline__ void gemm_core(
    const ushort_t* __restrict__ A, int lda, const ushort_t* __restrict__ B, int ldb,
    int r0, int c0, int K, ushort_t (*as)[64], ushort_t (*bs)[64], f4 acc[2][2])
{
    const int t = threadIdx.x;
    const int wave = t >> 6, lane = t & 63;
    const int wm = (wave & 1) * 32, wn = (wave >> 1) * 32;
    const int fm = lane & 15, fq = lane >> 4;

    const int m0q0 = wave * 16 + (lane >> 3);
    const int m0q1 = m0q0 + 8;
    const int cs0 = ((lane & 7) ^ (m0q0 & 7)) * 8;
    const int cs1 = ((lane & 7) ^ (m0q1 & 7)) * 8;
    const ushort_t* ga0 = A + (size_t)(r0 + m0q0) * lda + cs0;
    const ushort_t* ga1 = A + (size_t)(r0 + m0q1) * lda + cs1;
    const ushort_t* gb0 = B + (size_t)(c0 + m0q0) * ldb + cs0;
    const ushort_t* gb1 = B + (size_t)(c0 + m0q1) * ldb + cs1;
    ushort_t* la0 = &as[wave * 16][0];
    ushort_t* la1 = &as[wave * 16 + 8][0];
    ushort_t* lb0 = &bs[wave * 16][0];
    ushort_t* lb1 = &bs[wave * 16 + 8][0];
    const int ra0 = wm + fm, ra1 = wm + 16 + fm;
    const int rb0 = wn + fm, rb1 = wn + 16 + fm;

    for (int k0 = 0; k0 < K; k0 += 64) {
        __syncthreads();
        gl_lds16(ga0 + k0, la0);
        gl_lds16(ga1 + k0, la1);
        gl_lds16(gb0 + k0, lb0);
        gl_lds16(gb1 + k0, lb1);
        __syncthreads();
        #pragma unroll
        for (int kk = 0; kk < 2; ++kk) {
            const int cc = kk * 4 + fq;
            const s8 a0 = *(const s8*)&as[ra0][(cc ^ (ra0 & 7)) * 8];
            const s8 a1 = *(const s8*)&as[ra1][(cc ^ (ra1 & 7)) * 8];
            const s8 b0 = *(const s8*)&bs[rb0][(cc ^ (rb0 & 7)) * 8];
            const s8 b1 = *(const s8*)&bs[rb1][(cc ^ (rb1 & 7)) * 8];
            acc[0][0] = __builtin_amdgcn_mfma_f32_16x16x32_bf16(a0, b0, acc[0][0], 0, 0, 0);
            acc[0][1] = __builtin_amdgcn_mfma_f32_16x16x32_bf16(a0, b1, acc[0][1], 0, 0, 0);
            acc[1][0] = __builtin_amdgcn_mfma_f32_16x16x32_bf16(a1, b0, acc[1][0], 0, 0, 0);
            acc[1][1] = __builtin_amdgcn_mfma_f32_16x16x32_bf16(a1, b1, acc[1][1], 0, 0, 0);
        }
    }
}

__global__ __launch_bounds__(256) void gemm1_kernel(
    const ushort_t* __restrict__ xb, const ushort_t* __restrict__ Wcatb,
    const float* __restrict__ bm0, const float* __restrict__ bm1,
    const float* __restrict__ bhh,
    ushort_t* __restrict__ msgb, float* __restrict__ gh)
{
    __shared__ ushort_t as[64][64];
    __shared__ ushort_t bs[64][64];
    const int t = threadIdx.x;
    const int wave = t >> 6, lane = t & 63;
    const int wm = (wave & 1) * 32, wn = (wave >> 1) * 32;
    const int fm = lane & 15, fq = lane >> 4;
    const int c0 = blockIdx.x * 64, r0 = blockIdx.y * 64;
    f4 acc[2][2] = {};
    gemm_core(xb, DD, Wcatb, DD, r0, c0, DD, as, bs, acc);
    // C/D layout (m89-verified): col = lane&15, row = (lane>>4)*4 + reg
    #pragma unroll
    for (int ni = 0; ni < 2; ++ni) {
        const int col = c0 + wn + ni * 16 + fm;
        const float bv = (col < 256) ? bm0[col]
                       : (col < 512) ? bm1[col - 256]
                                     : bhh[col - 512];
        #pragma unroll
        for (int mi = 0; mi < 2; ++mi) {
            #pragma unroll
            for (int r = 0; r < 4; ++r) {
                const int row = r0 + wm + mi * 16 + fq * 4 + r;
                const float v = acc[mi][ni][r] + bv;
                if (col < 512) msgb[(size_t)row * 512 + col] = f2b(v);
                else           gh[(size_t)row * 768 + col - 512] = v;
            }
        }
    }
}

// ---------------------------------------------------------------------------
// K3: attn: compact 8 segments into LDS, edge-only softmax (== dense ref:
// exp(NEG-m) underflows to 0; isolated -> 0 via inv=0), aggregate bf16 msg.
// ---------------------------------------------------------------------------
__global__ __launch_bounds__(256) void attn_kernel(
    const int* __restrict__ cntg, const uint2* __restrict__ ejw,
    const float* __restrict__ acur, const float* __restrict__ anb,
    const float* __restrict__ ba0, const float* __restrict__ ba1,
    const ushort_t* __restrict__ msgb, ushort_t* __restrict__ mcatb)
{
    const int i = blockIdx.x, l = blockIdx.y, t = threadIdx.x;
    __shared__ float es[HH][ECAP];
    __shared__ int ejs[ECAP];
    __shared__ int scnt[NG];
    const float* ba = l ? ba1 : ba0;
    if (t < NG)
        scnt[t] = min(max(cntg[((size_t)l * NN + i) * NG + t], 0), SCAP);
    __syncthreads();
    float ac[HH];
    #pragma unroll
    for (int h = 0; h < HH; ++h) ac[h] = acur[((size_t)l * NN + i) * HH + h] + ba[h];
    int ne = 0;
    #pragma unroll
    for (int g = 0; g < NG; ++g) {
        const int cg = scnt[g];
        const int e = ne + t;
        if (t < cg && e < ECAP) {
            const uint2 pk = ejw[(((size_t)l * NN + i) * NG + g) * SCAP + t];
            const int j = (int)pk.x;
            const float wv = __uint_as_float(pk.y);
            ejs[e] = j;
            const float4 av = *(const float4*)(anb + ((size_t)l * NN + j) * HH);
            const float sv[4] = {av.x, av.y, av.z, av.w};
            #pragma unroll
            for (int h = 0; h < HH; ++h) {
                float s = sv[h] + ac[h];
                s = (s > 0.f) ? s : 0.2f * s;       // leaky_relu(0.2)
                es[h][e] = s * wv;
            }
        }
        ne += cg;
    }
    ne = min(ne, ECAP);
    __syncthreads();
    {
        const int h = t >> 6, lane = t & 63;
        float s0 = (lane < ne) ? es[h][lane] : -1e30f;
        float s1 = (lane + 64 < ne) ? es[h][lane + 64] : -1e30f;
        float m = fmaxf(s0, s1);
        #pragma unroll
        for (int off = 32; off; off >>= 1) m = fmaxf(m, __shfl_xor(m, off));
        const float p0 = expf(s0 - m), p1 = expf(s1 - m);
        float sum = p0 + p1;
        #pragma unroll
        for (int off = 32; off; off >>= 1) sum += __shfl_xor(sum, off);
        const float inv = (ne > 0) ? 1.f / sum : 0.f;
        es[h][lane] = p0 * inv;
        if (lane + 64 < ECAP) es[h][lane + 64] = p1 * inv;
    }
    __syncthreads();
    const int h = t >> 6;
    const int off = l * DD + t;
    float acc = 0.f;
    int e = 0;
    for (; e + 4 <= ne; e += 4) {
        const float v0 = b2f(msgb[(size_t)ejs[e + 0] * 512 + off]);
        const float v1 = b2f(msgb[(size_t)ejs[e + 1] * 512 + off]);
        const float v2 = b2f(msgb[(size_t)ejs[e + 2] * 512 + off]);
        const float v3 = b2f(msgb[(size_t)ejs[e + 3] * 512 + off]);
        acc = fmaf(es[h][e + 0], v0, acc);
        acc = fmaf(es[h][e + 1], v1, acc);
        acc = fmaf(es[h][e + 2], v2, acc);
        acc = fmaf(es[h][e + 3], v3, acc);
    }
    for (; e < ne; ++e)
        acc = fmaf(es[h][e], b2f(msgb[(size_t)ejs[e] * 512 + off]), acc);
    mcatb[(size_t)i * (2 * DD) + off] = f2b(acc);
}

// ---------------------------------------------------------------------------
// K4: gemm2: gi[2048,768] = mcatb @ wihb^T + bih   (K=512)
// ---------------------------------------------------------------------------
__global__ __launch_bounds__(256) void gemm2_kernel(
    const ushort_t* __restrict__ mcatb, const ushort_t* __restrict__ wihb,
    const float* __restrict__ bih, float* __restrict__ gi)
{
    __shared__ ushort_t as[64][64];
    __shared__ ushort_t bs[64][64];
    const int t = threadIdx.x;
    const int wave = t >> 6, lane = t & 63;
    const int wm = (wave & 1) * 32, wn = (wave >> 1) * 32;
    const int fm = lane & 15, fq = lane >> 4;
    const int c0 = blockIdx.x * 64, r0 = blockIdx.y * 64;
    f4 acc[2][2] = {};
    gemm_core(mcatb, 512, wihb, 512, r0, c0, 512, as, bs, acc);
    #pragma unroll
    for (int ni = 0; ni < 2; ++ni) {
        const int col = c0 + wn + ni * 16 + fm;
        const float bv = bih[col];
        #pragma unroll
        for (int mi = 0; mi < 2; ++mi)
            #pragma unroll
            for (int r = 0; r < 4; ++r)
                gi[(size_t)(r0 + wm + mi * 16 + fq * 4 + r) * 768 + col] =
                    acc[mi][ni][r] + bv;
    }
}

// ---------------------------------------------------------------------------
// K5: GRU gates + LayerNorm.
// ---------------------------------------------------------------------------
__global__ __launch_bounds__(256) void gates_ln(
    const float* __restrict__ gi, const float* __restrict__ gh, const float* __restrict__ x,
    const float* __restrict__ lng, const float* __restrict__ lnb, float* __restrict__ out)
{
    __shared__ float rs1[4], rs2[4];
    const int t = threadIdx.x;
    const int r0 = blockIdx.x * 4;
    const float gv = lng[t], bv = lnb[t];
    float hv[4];
    #pragma unroll
    for (int r = 0; r < 4; ++r) {
        const int row = r0 + r;
        const float gir = gi[(size_t)row * 768 + t];
        const float giz = gi[(size_t)row * 768 + 256 + t];
        const float gin = gi[(size_t)row * 768 + 512 + t];
        const float ghr = gh[(size_t)row * 768 + t];
        const float ghz = gh[(size_t)row * 768 + 256 + t];
        const float ghn = gh[(size_t)row * 768 + 512 + t];
        const float rr = 1.f / (1.f + expf(-(gir + ghr)));
        const float zz = 1.f / (1.f + expf(-(giz + ghz)));
        const float nn = tanhf(gin + rr * ghn);
        hv[r] = (1.f - zz) * nn + zz * x[(size_t)row * DD + t];
    }
    const int lane = t & 63, wid = t >> 6;
    for (int r = 0; r < 4; ++r) {
        float s1 = hv[r], s2 = hv[r] * hv[r];
        #pragma unroll
        for (int off = 32; off; off >>= 1) {
            s1 += __shfl_down(s1, off);
            s2 += __shfl_down(s2, off);
        }
        if (lane == 0) { rs1[wid] = s1; rs2[wid] = s2; }
        __syncthreads();
        const float sum = rs1[0] + rs1[1] + rs1[2] + rs1[3];
        const float sq  = rs2[0] + rs2[1] + rs2[2] + rs2[3];
        const float mu  = sum * (1.f / DD);
        const float var = sq * (1.f / DD) - mu * mu;
        const float inv = rsqrtf(var + 1e-5f);
        out[(size_t)(r0 + r) * DD + t] = (hv[r] - mu) * inv * gv + bv;
        __syncthreads();
    }
}

extern "C" void kernel_launch(void* const* d_in, const int* in_sizes, int n_in,
                              void* d_out, int out_size, void* d_ws, size_t ws_size,
                              hipStream_t stream)
{
    const float* x    = (const float*)d_in[0];
    const float* adj0 = (const float*)d_in[1];
    const float* adj1 = (const float*)d_in[2];
    const float* w0   = (const float*)d_in[3];
    const float* w1   = (const float*)d_in[4];
    const float* Wm0  = (const float*)d_in[5];
    const float* bm0  = (const float*)d_in[6];
    const float* Wa0  = (const float*)d_in[7];
    const float* ba0  = (const float*)d_in[8];
    const float* Wm1  = (const float*)d_in[9];
    const float* bm1  = (const float*)d_in[10];
    const float* Wa1  = (const float*)d_in[11];
    const float* ba1  = (const float*)d_in[12];
    const float* wih  = (const float*)d_in[13];
    const float* whh  = (const float*)d_in[14];
    const float* bih  = (const float*)d_in[15];
    const float* bhh  = (const float*)d_in[16];
    const float* lng  = (const float*)d_in[17];
    const float* lnb  = (const float*)d_in[18];
    float* out = (float*)d_out;

    float* ws = (float*)d_ws;
    float* gh   = ws;            ws += (size_t)NN * 768;
    float* gi   = ws;            ws += (size_t)NN * 768;
    float* acur = ws;            ws += 2 * NN * HH;
    float* anb  = ws;            ws += 2 * NN * HH;
    int*   cntg = (int*)ws;      ws += 2 * NN * NG;
    uint2* ejw  = (uint2*)ws;    ws += 2 * 2 * NN * NG * SCAP;
    ushort_t* xb    = (ushort_t*)ws;  ws += (size_t)NN * DD / 2;
    ushort_t* Wcatb = (ushort_t*)ws;  ws += (size_t)PW * DD / 2;
    ushort_t* wihb  = (ushort_t*)ws;  ws += (size_t)768 * 512 / 2;
    ushort_t* msgb  = (ushort_t*)ws;  ws += (size_t)NN * 512 / 2;
    ushort_t* mcatb = (ushort_t*)ws;  ws += (size_t)NN * 512 / 2;
    // total ~27 MB

    prep_kernel<<<E_NB, 256, 0, stream>>>(
        x, adj0, adj1, w0, w1, Wm0, Wm1, whh, wih, Wa0, Wa1,
        cntg, ejw, xb, Wcatb, wihb, acur, anb);
    gemm1_kernel<<<dim3(PW / 64, NN / 64), 256, 0, stream>>>(
        xb, Wcatb, bm0, bm1, bhh, msgb, gh);
    attn_kernel<<<dim3(NN, 2), 256, 0, stream>>>(
        cntg, ejw, acur, anb, ba0, ba1, msgb, mcatb);
    gemm2_kernel<<<dim3(12, 32), 256, 0, stream>>>(mcatb, wihb, bih, gi);
    gates_ln<<<NN / 4, 256, 0, stream>>>(gi, gh, x, lng, lnb, out);
}

// Round 14
// 176.412 us; speedup vs baseline: 1.1659x; 1.1659x over previous
//
#include <hip/hip_runtime.h>

#define NN 2048
#define DD 256
#define HH 4
#define PW 1280      // gemm1 output width: 256 msg0 | 256 msg1 | 768 gh
#define ECAP 128

typedef unsigned short ushort_t;
typedef __attribute__((ext_vector_type(4))) unsigned short us4;
typedef __attribute__((ext_vector_type(8))) short s8;
typedef __attribute__((ext_vector_type(4))) float f4;

__device__ __forceinline__ ushort_t f2b(float f) {   // fp32 -> bf16 bits, RNE
    unsigned int u = __float_as_uint(f);
    return (ushort_t)((u + 0x7fffu + ((u >> 16) & 1u)) >> 16);
}
__device__ __forceinline__ float b2f(ushort_t b) {
    return __uint_as_float(((unsigned int)b) << 16);
}
__device__ __forceinline__ void gl_lds16(const void* g, void* l) {
    __builtin_amdgcn_global_load_lds(
        (const __attribute__((address_space(1))) void*)g,
        (__attribute__((address_space(3))) void*)l, 16, 0, 0);
}

// ---------------------------------------------------------------------------
// K1 prep: conversions + attn_proj only (~8.5 MB streamed, fast).
//  [0,512)      xb = bf16(x)
//  [512,832)    Wcatb = bf16([Wm0;Wm1;whh])
//  [832,1216)   wihb = bf16(wih)
//  [1216,1344)  attn_proj: acur/anb (fp32 exact)
// ---------------------------------------------------------------------------
#define P_XC  512
#define P_WC  832
#define P_WI  1216
#define P_NB  1344

__global__ __launch_bounds__(256) void prep_kernel(
    const float* __restrict__ x,
    const float* __restrict__ Wm0, const float* __restrict__ Wm1,
    const float* __restrict__ whh, const float* __restrict__ wih,
    const float* __restrict__ Wa0, const float* __restrict__ Wa1,
    ushort_t* __restrict__ xb, ushort_t* __restrict__ Wcatb, ushort_t* __restrict__ wihb,
    float* __restrict__ acur, float* __restrict__ anb)
{
    __shared__ float sh[16][257];
    const int b = blockIdx.x, t = threadIdx.x;

    if (b < P_XC) {                        // ---- x -> bf16 ----
        const int id = b * 1024 + t * 4;
        const float4 v = *(const float4*)(x + id);
        us4 o; o.x = f2b(v.x); o.y = f2b(v.y); o.z = f2b(v.z); o.w = f2b(v.w);
        *(us4*)(xb + id) = o;
        return;
    }
    if (b < P_WC) {                        // ---- [Wm0;Wm1;whh] -> bf16 ----
        const int id = (b - P_XC) * 1024 + t * 4;
        const int c = id >> 8, k = id & 255;
        const float* src = (c < 256) ? Wm0 + (size_t)c * DD + k
                         : (c < 512) ? Wm1 + (size_t)(c - 256) * DD + k
                                     : whh + (size_t)(c - 512) * DD + k;
        const float4 v = *(const float4*)src;
        us4 o; o.x = f2b(v.x); o.y = f2b(v.y); o.z = f2b(v.z); o.w = f2b(v.w);
        *(us4*)(Wcatb + id) = o;
        return;
    }
    if (b < P_WI) {                        // ---- wih -> bf16 ----
        const int id = (b - P_WC) * 1024 + t * 4;
        const float4 v = *(const float4*)(wih + id);
        us4 o; o.x = f2b(v.x); o.y = f2b(v.y); o.z = f2b(v.z); o.w = f2b(v.w);
        *(us4*)(wihb + id) = o;
        return;
    }
    {                                      // ---- attn_proj ----
        const int i0 = (b - P_WI) * 16;
        for (int rr = 0; rr < 16; ++rr)
            sh[rr][t] = x[(size_t)(i0 + rr) * DD + t];
        __syncthreads();
        const int r = t >> 4, idx = t & 15;
        const int l = idx >> 3, isnb = (idx >> 2) & 1, h = idx & 3;
        const float* wrow = (l ? Wa1 : Wa0) + h * (2 * DD) + isnb * DD;
        float acc = 0.f;
        for (int k = 0; k < DD; ++k) acc = fmaf(sh[r][k], wrow[k], acc);
        float* dst = isnb ? anb : acur;
        dst[((size_t)l * NN + i0 + r) * HH + h] = acc;
    }
}

// ---------------------------------------------------------------------------
// shared MFMA gemm core (as in r10-12): 64x64 tile, global_load_lds 16B
// staging into unpadded [64][64] with XOR chunk swizzle.
// ---------------------------------------------------------------------------
__device__ __forceinline__ void gemm_core(
    const ushort_t* __restrict__ A, int lda, const ushort_t* __restrict__ B, int ldb,
    int r0, int c0, int K, ushort_t (*as)[64], ushort_t (*bs)[64], f4 acc[2][2])
{
    const int t = threadIdx.x;
    const int wave = t >> 6, lane = t & 63;
    const int wm = (wave & 1) * 32, wn = (wave >> 1) * 32;
    const int fm = lane & 15, fq = lane >> 4;

    const int m0q0 = wave * 16 + (lane >> 3);
    const int m0q1 = m0q0 + 8;
    const int cs0 = ((lane & 7) ^ (m0q0 & 7)) * 8;
    const int cs1 = ((lane & 7) ^ (m0q1 & 7)) * 8;
    const ushort_t* ga0 = A + (size_t)(r0 + m0q0) * lda + cs0;
    const ushort_t* ga1 = A + (size_t)(r0 + m0q1) * lda + cs1;
    const ushort_t* gb0 = B + (size_t)(c0 + m0q0) * ldb + cs0;
    const ushort_t* gb1 = B + (size_t)(c0 + m0q1) * ldb + cs1;
    ushort_t* la0 = &as[wave * 16][0];
    ushort_t* la1 = &as[wave * 16 + 8][0];
    ushort_t* lb0 = &bs[wave * 16][0];
    ushort_t* lb1 = &bs[wave * 16 + 8][0];
    const int ra0 = wm + fm, ra1 = wm + 16 + fm;
    const int rb0 = wn + fm, rb1 = wn + 16 + fm;

    for (int k0 = 0; k0 < K; k0 += 64) {
        __syncthreads();
        gl_lds16(ga0 + k0, la0);
        gl_lds16(ga1 + k0, la1);
        gl_lds16(gb0 + k0, lb0);
        gl_lds16(gb1 + k0, lb1);
        __syncthreads();
        #pragma unroll
        for (int kk = 0; kk < 2; ++kk) {
            const int cc = kk * 4 + fq;
            const s8 a0 = *(const s8*)&as[ra0][(cc ^ (ra0 & 7)) * 8];
            const s8 a1 = *(const s8*)&as[ra1][(cc ^ (ra1 & 7)) * 8];
            const s8 b0 = *(const s8*)&bs[rb0][(cc ^ (rb0 & 7)) * 8];
            const s8 b1 = *(const s8*)&bs[rb1][(cc ^ (rb1 & 7)) * 8];
            acc[0][0] = __builtin_amdgcn_mfma_f32_16x16x32_bf16(a0, b0, acc[0][0], 0, 0, 0);
            acc[0][1] = __builtin_amdgcn_mfma_f32_16x16x32_bf16(a0, b1, acc[0][1], 0, 0, 0);
            acc[1][0] = __builtin_amdgcn_mfma_f32_16x16x32_bf16(a1, b0, acc[1][0], 0, 0, 0);
            acc[1][1] = __builtin_amdgcn_mfma_f32_16x16x32_bf16(a1, b1, acc[1][1], 0, 0, 0);
        }
    }
}

// ---------------------------------------------------------------------------
// K2 union: [0,640) gemm1 tiles (MFMA-bound) + [640,896) adj-only edge scan
// (latency-bound, idle VALU/MFMA) — co-resident blocks overlap pipes (m114);
// dispatch time ~ max, not sum. Edge scan: block = (16-col chunk, layer),
// r12 structure (best measured), adj only, j-index stored (w gathered later
// in attn). LDS counters; block owns its cnt words -> no global atomics.
// ---------------------------------------------------------------------------
__global__ __launch_bounds__(256) void gemm1_edge_kernel(
    const ushort_t* __restrict__ xb, const ushort_t* __restrict__ Wcatb,
    const float* __restrict__ bm0, const float* __restrict__ bm1,
    const float* __restrict__ bhh,
    ushort_t* __restrict__ msgb, float* __restrict__ gh,
    const float* __restrict__ adj0, const float* __restrict__ adj1,
    int* __restrict__ cnt, int* __restrict__ ej)
{
    __shared__ ushort_t as[64][64];
    __shared__ ushort_t bs[64][64];
    const int b = blockIdx.x, t = threadIdx.x;

    if (b < 640) {                         // ---- gemm1 tile ----
        const int wave = t >> 6, lane = t & 63;
        const int wm = (wave & 1) * 32, wn = (wave >> 1) * 32;
        const int fm = lane & 15, fq = lane >> 4;
        const int c0 = (b % 20) * 64, r0 = (b / 20) * 64;
        f4 acc[2][2] = {};
        gemm_core(xb, DD, Wcatb, DD, r0, c0, DD, as, bs, acc);
        // C/D layout (m89-verified): col = lane&15, row = (lane>>4)*4 + reg
        #pragma unroll
        for (int ni = 0; ni < 2; ++ni) {
            const int col = c0 + wn + ni * 16 + fm;
            const float bv = (col < 256) ? bm0[col]
                           : (col < 512) ? bm1[col - 256]
                                         : bhh[col - 512];
            #pragma unroll
            for (int mi = 0; mi < 2; ++mi) {
                #pragma unroll
                for (int r = 0; r < 4; ++r) {
                    const int row = r0 + wm + mi * 16 + fq * 4 + r;
                    const float v = acc[mi][ni][r] + bv;
                    if (col < 512) msgb[(size_t)row * 512 + col] = f2b(v);
                    else           gh[(size_t)row * 768 + col - 512] = v;
                }
            }
        }
        return;
    }
    {                                      // ---- adj-only edge scan ----
        const int eb = b - 640;
        const int l = eb & 1, chunk = eb >> 1;
        const int i0 = chunk * 16;
        const float* adj = l ? adj1 : adj0;
        int* lcnt = (int*)as;              // 16 LDS counters
        if (t < 16) lcnt[t] = 0;
        __syncthreads();
        const int rowLane = t >> 2, q = t & 3;
        for (int r0r = 0; r0r < NN; r0r += 512) {
            float4 a[8];
            #pragma unroll
            for (int it = 0; it < 8; ++it) {
                const int j = r0r + it * 64 + rowLane;
                a[it] = *(const float4*)(adj + (size_t)j * NN + i0 + q * 4);
            }
            #pragma unroll
            for (int it = 0; it < 8; ++it) {
                const int j = r0r + it * 64 + rowLane;
                const float av[4] = {a[it].x, a[it].y, a[it].z, a[it].w};
                #pragma unroll
                for (int u = 0; u < 4; ++u) {
                    if (av[u] != 0.f) {
                        const int li = q * 4 + u;
                        const int slot = atomicAdd(&lcnt[li], 1);
                        if (slot < ECAP)
                            ej[((size_t)l * NN + i0 + li) * ECAP + slot] = j;
                    }
                }
            }
        }
        __syncthreads();
        if (t < 16) cnt[l * NN + i0 + t] = min(lcnt[t], ECAP);
    }
}

// ---------------------------------------------------------------------------
// K3 attn: gather w per edge (31 independent 4B gathers/block, 4096 blocks),
// edge-only softmax (== dense ref: exp(NEG-m) underflows to 0; isolated -> 0
// via inv=0), aggregate bf16 msg rows -> bf16 mcat.
// ---------------------------------------------------------------------------
__global__ __launch_bounds__(256) void attn_kernel(
    const int* __restrict__ cnt, const int* __restrict__ ej,
    const float* __restrict__ w0, const float* __restrict__ w1,
    const float* __restrict__ acur, const float* __restrict__ anb,
    const float* __restrict__ ba0, const float* __restrict__ ba1,
    const ushort_t* __restrict__ msgb, ushort_t* __restrict__ mcatb)
{
    const int i = blockIdx.x, l = blockIdx.y, t = threadIdx.x;
    __shared__ float es[HH][ECAP];
    __shared__ int ejs[ECAP];
    const int ne = min(max(cnt[l * NN + i], 0), ECAP);
    const float* ba = l ? ba1 : ba0;
    const float* w  = l ? w1 : w0;
    const size_t ebase = ((size_t)l * NN + i) * ECAP;

    if (t < ne) {
        const int j = ej[ebase + t];
        const float wv = w[(size_t)j * NN + i];   // gather (latency-parallel)
        ejs[t] = j;
        const float4 av = *(const float4*)(anb + ((size_t)l * NN + j) * HH);
        const float sv[4] = {av.x, av.y, av.z, av.w};
        #pragma unroll
        for (int h = 0; h < HH; ++h) {
            float s = sv[h] + acur[((size_t)l * NN + i) * HH + h] + ba[h];
            s = (s > 0.f) ? s : 0.2f * s;           // leaky_relu(0.2)
            es[h][t] = s * wv;
        }
    }
    __syncthreads();
    {
        const int h = t >> 6, lane = t & 63;
        float s0 = (lane < ne) ? es[h][lane] : -1e30f;
        float s1 = (lane + 64 < ne) ? es[h][lane + 64] : -1e30f;
        float m = fmaxf(s0, s1);
        #pragma unroll
        for (int off = 32; off; off >>= 1) m = fmaxf(m, __shfl_xor(m, off));
        const float p0 = expf(s0 - m), p1 = expf(s1 - m);
        float sum = p0 + p1;
        #pragma unroll
        for (int off = 32; off; off >>= 1) sum += __shfl_xor(sum, off);
        const float inv = (ne > 0) ? 1.f / sum : 0.f;
        es[h][lane] = p0 * inv;
        if (lane + 64 < ECAP) es[h][lane + 64] = p1 * inv;
    }
    __syncthreads();
    const int h = t >> 6;
    const int off = l * DD + t;
    float acc = 0.f;
    int e = 0;
    for (; e + 4 <= ne; e += 4) {
        const float v0 = b2f(msgb[(size_t)ejs[e + 0] * 512 + off]);
        const float v1 = b2f(msgb[(size_t)ejs[e + 1] * 512 + off]);
        const float v2 = b2f(msgb[(size_t)ejs[e + 2] * 512 + off]);
        const float v3 = b2f(msgb[(size_t)ejs[e + 3] * 512 + off]);
        acc = fmaf(es[h][e + 0], v0, acc);
        acc = fmaf(es[h][e + 1], v1, acc);
        acc = fmaf(es[h][e + 2], v2, acc);
        acc = fmaf(es[h][e + 3], v3, acc);
    }
    for (; e < ne; ++e)
        acc = fmaf(es[h][e], b2f(msgb[(size_t)ejs[e] * 512 + off]), acc);
    mcatb[(size_t)i * (2 * DD) + off] = f2b(acc);
}

// ---------------------------------------------------------------------------
// K4: gemm2: gi[2048,768] = mcatb @ wihb^T + bih   (K=512)
// ---------------------------------------------------------------------------
__global__ __launch_bounds__(256) void gemm2_kernel(
    const ushort_t* __restrict__ mcatb, const ushort_t* __restrict__ wihb,
    const float* __restrict__ bih, float* __restrict__ gi)
{
    __shared__ ushort_t as[64][64];
    __shared__ ushort_t bs[64][64];
    const int t = threadIdx.x;
    const int wave = t >> 6, lane = t & 63;
    const int wm = (wave & 1) * 32, wn = (wave >> 1) * 32;
    const int fm = lane & 15, fq = lane >> 4;
    const int c0 = blockIdx.x * 64, r0 = blockIdx.y * 64;
    f4 acc[2][2] = {};
    gemm_core(mcatb, 512, wihb, 512, r0, c0, 512, as, bs, acc);
    #pragma unroll
    for (int ni = 0; ni < 2; ++ni) {
        const int col = c0 + wn + ni * 16 + fm;
        const float bv = bih[col];
        #pragma unroll
        for (int mi = 0; mi < 2; ++mi)
            #pragma unroll
            for (int r = 0; r < 4; ++r)
                gi[(size_t)(r0 + wm + mi * 16 + fq * 4 + r) * 768 + col] =
                    acc[mi][ni][r] + bv;
    }
}

// ---------------------------------------------------------------------------
// K5: GRU gates + LayerNorm.
// ---------------------------------------------------------------------------
__global__ __launch_bounds__(256) void gates_ln(
    const float* __restrict__ gi, const float* __restrict__ gh, const float* __restrict__ x,
    const float* __restrict__ lng, const float* __restrict__ lnb, float* __restrict__ out)
{
    __shared__ float rs1[4], rs2[4];
    const int t = threadIdx.x;
    const int r0 = blockIdx.x * 4;
    const float gv = lng[t], bv = lnb[t];
    float hv[4];
    #pragma unroll
    for (int r = 0; r < 4; ++r) {
        const int row = r0 + r;
        const float gir = gi[(size_t)row * 768 + t];
        const float giz = gi[(size_t)row * 768 + 256 + t];
        const float gin = gi[(size_t)row * 768 + 512 + t];
        const float ghr = gh[(size_t)row * 768 + t];
        const float ghz = gh[(size_t)row * 768 + 256 + t];
        const float ghn = gh[(size_t)row * 768 + 512 + t];
        const float rr = 1.f / (1.f + expf(-(gir + ghr)));
        const float zz = 1.f / (1.f + expf(-(giz + ghz)));
        const float nn = tanhf(gin + rr * ghn);
        hv[r] = (1.f - zz) * nn + zz * x[(size_t)row * DD + t];
    }
    const int lane = t & 63, wid = t >> 6;
    for (int r = 0; r < 4; ++r) {
        float s1 = hv[r], s2 = hv[r] * hv[r];
        #pragma unroll
        for (int off = 32; off; off >>= 1) {
            s1 += __shfl_down(s1, off);
            s2 += __shfl_down(s2, off);
        }
        if (lane == 0) { rs1[wid] = s1; rs2[wid] = s2; }
        __syncthreads();
        const float sum = rs1[0] + rs1[1] + rs1[2] + rs1[3];
        const float sq  = rs2[0] + rs2[1] + rs2[2] + rs2[3];
        const float mu  = sum * (1.f / DD);
        const float var = sq * (1.f / DD) - mu * mu;
        const float inv = rsqrtf(var + 1e-5f);
        out[(size_t)(r0 + r) * DD + t] = (hv[r] - mu) * inv * gv + bv;
        __syncthreads();
    }
}

extern "C" void kernel_launch(void* const* d_in, const int* in_sizes, int n_in,
                              void* d_out, int out_size, void* d_ws, size_t ws_size,
                              hipStream_t stream)
{
    const float* x    = (const float*)d_in[0];
    const float* adj0 = (const float*)d_in[1];
    const float* adj1 = (const float*)d_in[2];
    const float* w0   = (const float*)d_in[3];
    const float* w1   = (const float*)d_in[4];
    const float* Wm0  = (const float*)d_in[5];
    const float* bm0  = (const float*)d_in[6];
    const float* Wa0  = (const float*)d_in[7];
    const float* ba0  = (const float*)d_in[8];
    const float* Wm1  = (const float*)d_in[9];
    const float* bm1  = (const float*)d_in[10];
    const float* Wa1  = (const float*)d_in[11];
    const float* ba1  = (const float*)d_in[12];
    const float* wih  = (const float*)d_in[13];
    const float* whh  = (const float*)d_in[14];
    const float* bih  = (const float*)d_in[15];
    const float* bhh  = (const float*)d_in[16];
    const float* lng  = (const float*)d_in[17];
    const float* lnb  = (const float*)d_in[18];
    float* out = (float*)d_out;

    float* ws = (float*)d_ws;
    float* gh   = ws;            ws += (size_t)NN * 768;
    float* gi   = ws;            ws += (size_t)NN * 768;
    float* acur = ws;            ws += 2 * NN * HH;
    float* anb  = ws;            ws += 2 * NN * HH;
    int*   cnt  = (int*)ws;      ws += 2 * NN;
    int*   ej   = (int*)ws;      ws += 2 * NN * ECAP;
    ushort_t* xb    = (ushort_t*)ws;  ws += (size_t)NN * DD / 2;
    ushort_t* Wcatb = (ushort_t*)ws;  ws += (size_t)PW * DD / 2;
    ushort_t* wihb  = (ushort_t*)ws;  ws += (size_t)768 * 512 / 2;
    ushort_t* msgb  = (ushort_t*)ws;  ws += (size_t)NN * 512 / 2;
    ushort_t* mcatb = (ushort_t*)ws;  ws += (size_t)NN * 512 / 2;
    // total ~20 MB

    prep_kernel<<<P_NB, 256, 0, stream>>>(
        x, Wm0, Wm1, whh, wih, Wa0, Wa1, xb, Wcatb, wihb, acur, anb);
    gemm1_edge_kernel<<<896, 256, 0, stream>>>(
        xb, Wcatb, bm0, bm1, bhh, msgb, gh, adj0, adj1, cnt, ej);
    attn_kernel<<<dim3(NN, 2), 256, 0, stream>>>(
        cnt, ej, w0, w1, acur, anb, ba0, ba1, msgb, mcatb);
    gemm2_kernel<<<dim3(12, 32), 256, 0, stream>>>(mcatb, wihb, bih, gi);
    gates_ln<<<NN / 4, 256, 0, stream>>>(gi, gh, x, lng, lnb, out);
}

// Round 15
// 168.708 us; speedup vs baseline: 1.2191x; 1.0457x over previous
//
#include <hip/hip_runtime.h>

#define NN 2048
#define DD 256
#define HH 4
#define ECAP 128

typedef unsigned short ushort_t;
typedef __attribute__((ext_vector_type(4))) unsigned short us4;
typedef __attribute__((ext_vector_type(8))) unsigned short us8;
typedef __attribute__((ext_vector_type(8))) short s8;
typedef __attribute__((ext_vector_type(4))) float f4;

__device__ __forceinline__ ushort_t f2b(float f) {   // fp32 -> bf16 bits, RNE
    unsigned int u = __float_as_uint(f);
    return (ushort_t)((u + 0x7fffu + ((u >> 16) & 1u)) >> 16);
}
__device__ __forceinline__ float b2f(ushort_t b) {
    return __uint_as_float(((unsigned int)b) << 16);
}
__device__ __forceinline__ void gl_lds16(const void* g, void* l) {
    __builtin_amdgcn_global_load_lds(
        (const __attribute__((address_space(1))) void*)g,
        (__attribute__((address_space(3))) void*)l, 16, 0, 0);
}

// ---------------------------------------------------------------------------
// bf16 gemm core (gl_lds staging, XOR-swizzled [64][64]) — used by gemm2.
// ---------------------------------------------------------------------------
__device__ __forceinline__ void gemm_core(
    const ushort_t* __restrict__ A, int lda, const ushort_t* __restrict__ B, int ldb,
    int r0, int c0, int K, ushort_t (*as)[64], ushort_t (*bs)[64], f4 acc[2][2])
{
    const int t = threadIdx.x;
    const int wave = t >> 6, lane = t & 63;
    const int wm = (wave & 1) * 32, wn = (wave >> 1) * 32;
    const int fm = lane & 15, fq = lane >> 4;

    const int m0q0 = wave * 16 + (lane >> 3);
    const int m0q1 = m0q0 + 8;
    const int cs0 = ((lane & 7) ^ (m0q0 & 7)) * 8;
    const int cs1 = ((lane & 7) ^ (m0q1 & 7)) * 8;
    const ushort_t* ga0 = A + (size_t)(r0 + m0q0) * lda + cs0;
    const ushort_t* ga1 = A + (size_t)(r0 + m0q1) * lda + cs1;
    const ushort_t* gb0 = B + (size_t)(c0 + m0q0) * ldb + cs0;
    const ushort_t* gb1 = B + (size_t)(c0 + m0q1) * ldb + cs1;
    ushort_t* la0 = &as[wave * 16][0];
    ushort_t* la1 = &as[wave * 16 + 8][0];
    ushort_t* lb0 = &bs[wave * 16][0];
    ushort_t* lb1 = &bs[wave * 16 + 8][0];
    const int ra0 = wm + fm, ra1 = wm + 16 + fm;
    const int rb0 = wn + fm, rb1 = wn + 16 + fm;

    for (int k0 = 0; k0 < K; k0 += 64) {
        __syncthreads();
        gl_lds16(ga0 + k0, la0);
        gl_lds16(ga1 + k0, la1);
        gl_lds16(gb0 + k0, lb0);
        gl_lds16(gb1 + k0, lb1);
        __syncthreads();
        #pragma unroll
        for (int kk = 0; kk < 2; ++kk) {
            const int cc = kk * 4 + fq;
            const s8 a0 = *(const s8*)&as[ra0][(cc ^ (ra0 & 7)) * 8];
            const s8 a1 = *(const s8*)&as[ra1][(cc ^ (ra1 & 7)) * 8];
            const s8 b0 = *(const s8*)&bs[rb0][(cc ^ (rb0 & 7)) * 8];
            const s8 b1 = *(const s8*)&bs[rb1][(cc ^ (rb1 & 7)) * 8];
            acc[0][0] = __builtin_amdgcn_mfma_f32_16x16x32_bf16(a0, b0, acc[0][0], 0, 0, 0);
            acc[0][1] = __builtin_amdgcn_mfma_f32_16x16x32_bf16(a0, b1, acc[0][1], 0, 0, 0);
            acc[1][0] = __builtin_amdgcn_mfma_f32_16x16x32_bf16(a1, b0, acc[1][0], 0, 0, 0);
            acc[1][1] = __builtin_amdgcn_mfma_f32_16x16x32_bf16(a1, b1, acc[1][1], 0, 0, 0);
        }
    }
}

// ---------------------------------------------------------------------------
// fp32-input gemm core: identical tile geometry/LDS layout, but staging loads
// fp32, converts to bf16 in-register (RNE — bit-identical to prep's convert),
// and ds_write_b128s into the same XOR-swizzled layout. Global loads issue
// before the barrier -> overlap previous k-step's MFMA.
// ---------------------------------------------------------------------------
__device__ __forceinline__ us8 cvt8(float4 a, float4 b) {
    us8 o;
    o[0] = f2b(a.x); o[1] = f2b(a.y); o[2] = f2b(a.z); o[3] = f2b(a.w);
    o[4] = f2b(b.x); o[5] = f2b(b.y); o[6] = f2b(b.z); o[7] = f2b(b.w);
    return o;
}

__device__ __forceinline__ void gemm_core_f32(
    const float* __restrict__ A, int lda, const float* __restrict__ B, int ldb,
    int r0, int c0, int K, ushort_t (*as)[64], ushort_t (*bs)[64], f4 acc[2][2])
{
    const int t = threadIdx.x;
    const int wave = t >> 6, lane = t & 63;
    const int wm = (wave & 1) * 32, wn = (wave >> 1) * 32;
    const int fm = lane & 15, fq = lane >> 4;

    const int m1 = wave * 16 + (lane >> 3);
    const int m2 = m1 + 8;
    const int g1 = ((lane & 7) ^ (m1 & 7)) * 8;   // global elem offset (swizzled)
    const int g2 = ((lane & 7) ^ (m2 & 7)) * 8;
    const int cl = (lane & 7) * 8;                // LDS chunk offset
    const int ra0 = wm + fm, ra1 = wm + 16 + fm;
    const int rb0 = wn + fm, rb1 = wn + 16 + fm;

    for (int k0 = 0; k0 < K; k0 += 64) {
        const float4 aa0 = *(const float4*)(A + (size_t)(r0 + m1) * lda + k0 + g1);
        const float4 aa1 = *(const float4*)(A + (size_t)(r0 + m1) * lda + k0 + g1 + 4);
        const float4 ab0 = *(const float4*)(A + (size_t)(r0 + m2) * lda + k0 + g2);
        const float4 ab1 = *(const float4*)(A + (size_t)(r0 + m2) * lda + k0 + g2 + 4);
        const float4 ba0 = *(const float4*)(B + (size_t)(c0 + m1) * ldb + k0 + g1);
        const float4 ba1 = *(const float4*)(B + (size_t)(c0 + m1) * ldb + k0 + g1 + 4);
        const float4 bb0 = *(const float4*)(B + (size_t)(c0 + m2) * ldb + k0 + g2);
        const float4 bb1 = *(const float4*)(B + (size_t)(c0 + m2) * ldb + k0 + g2 + 4);
        __syncthreads();                       // prev compute done, LDS free
        *(us8*)&as[m1][cl] = cvt8(aa0, aa1);
        *(us8*)&as[m2][cl] = cvt8(ab0, ab1);
        *(us8*)&bs[m1][cl] = cvt8(ba0, ba1);
        *(us8*)&bs[m2][cl] = cvt8(bb0, bb1);
        __syncthreads();
        #pragma unroll
        for (int kk = 0; kk < 2; ++kk) {
            const int cc = kk * 4 + fq;
            const s8 a0 = *(const s8*)&as[ra0][(cc ^ (ra0 & 7)) * 8];
            const s8 a1 = *(const s8*)&as[ra1][(cc ^ (ra1 & 7)) * 8];
            const s8 b0 = *(const s8*)&bs[rb0][(cc ^ (rb0 & 7)) * 8];
            const s8 b1 = *(const s8*)&bs[rb1][(cc ^ (rb1 & 7)) * 8];
            acc[0][0] = __builtin_amdgcn_mfma_f32_16x16x32_bf16(a0, b0, acc[0][0], 0, 0, 0);
            acc[0][1] = __builtin_amdgcn_mfma_f32_16x16x32_bf16(a0, b1, acc[0][1], 0, 0, 0);
            acc[1][0] = __builtin_amdgcn_mfma_f32_16x16x32_bf16(a1, b0, acc[1][0], 0, 0, 0);
            acc[1][1] = __builtin_amdgcn_mfma_f32_16x16x32_bf16(a1, b1, acc[1][1], 0, 0, 0);
        }
    }
}

// ---------------------------------------------------------------------------
// K1 union (everything that reads only inputs — prep is GONE):
//  [0,256)      edge scan (adj only; LDS counters; block owns cnt words)
//  [256,384)    attn_proj: acur/anb (fp32 exact)
//  [384,768)    wihb = bf16(wih)  (gemm2's B operand)
//  [768,1408)   gemm1 tiles, fp32 inline-convert staging:
//               [msg0|msg1|gh] = x @ [Wm0;Wm1;whh]^T + bias. B-source select
//               is per-block uniform (region boundaries are multiples of 64).
// Scan blocks launch FIRST so their memory streams start before gemm tiles
// fill the CUs; the two groups overlap pipes (m114), dispatch ~ max not sum.
// ---------------------------------------------------------------------------
#define E_SC  256
#define E_AP  384
#define E_WI  768
#define E_NB  1408

__global__ __launch_bounds__(256) void fused1_kernel(
    const float* __restrict__ x,
    const float* __restrict__ adj0, const float* __restrict__ adj1,
    const float* __restrict__ Wm0, const float* __restrict__ Wm1,
    const float* __restrict__ whh, const float* __restrict__ wih,
    const float* __restrict__ Wa0, const float* __restrict__ Wa1,
    const float* __restrict__ bm0, const float* __restrict__ bm1,
    const float* __restrict__ bhh,
    int* __restrict__ cnt, int* __restrict__ ej,
    ushort_t* __restrict__ wihb,
    float* __restrict__ acur, float* __restrict__ anb,
    ushort_t* __restrict__ msgb, float* __restrict__ gh)
{
    __shared__ char smem[16448];               // max(gemm 16384, attn_proj 16448)
    const int b = blockIdx.x, t = threadIdx.x;

    if (b < E_SC) {                            // ---- adj-only edge scan ----
        const int l = b & 1, chunk = b >> 1;
        const int i0 = chunk * 16;
        const float* adj = l ? adj1 : adj0;
        int* lcnt = (int*)smem;
        if (t < 16) lcnt[t] = 0;
        __syncthreads();
        const int rowLane = t >> 2, q = t & 3;
        for (int r0r = 0; r0r < NN; r0r += 512) {
            float4 a[8];
            #pragma unroll
            for (int it = 0; it < 8; ++it) {
                const int j = r0r + it * 64 + rowLane;
                a[it] = *(const float4*)(adj + (size_t)j * NN + i0 + q * 4);
            }
            #pragma unroll
            for (int it = 0; it < 8; ++it) {
                const int j = r0r + it * 64 + rowLane;
                const float av[4] = {a[it].x, a[it].y, a[it].z, a[it].w};
                #pragma unroll
                for (int u = 0; u < 4; ++u) {
                    if (av[u] != 0.f) {
                        const int li = q * 4 + u;
                        const int slot = atomicAdd(&lcnt[li], 1);
                        if (slot < ECAP)
                            ej[((size_t)l * NN + i0 + li) * ECAP + slot] = j;
                    }
                }
            }
        }
        __syncthreads();
        if (t < 16) cnt[l * NN + i0 + t] = min(lcnt[t], ECAP);
        return;
    }
    if (b < E_AP) {                            // ---- attn_proj ----
        float* sh = (float*)smem;              // [16][257]
        const int i0 = (b - E_SC) * 16;
        for (int rr = 0; rr < 16; ++rr)
            sh[rr * 257 + t] = x[(size_t)(i0 + rr) * DD + t];
        __syncthreads();
        const int r = t >> 4, idx = t & 15;
        const int l = idx >> 3, isnb = (idx >> 2) & 1, h = idx & 3;
        const float* wrow = (l ? Wa1 : Wa0) + h * (2 * DD) + isnb * DD;
        float acc = 0.f;
        for (int k = 0; k < DD; ++k) acc = fmaf(sh[r * 257 + k], wrow[k], acc);
        float* dst = isnb ? anb : acur;
        dst[((size_t)l * NN + i0 + r) * HH + h] = acc;
        return;
    }
    if (b < E_WI) {                            // ---- wih -> bf16 ----
        const int id = (b - E_AP) * 1024 + t * 4;
        const float4 v = *(const float4*)(wih + id);
        us4 o; o.x = f2b(v.x); o.y = f2b(v.y); o.z = f2b(v.z); o.w = f2b(v.w);
        *(us4*)(wihb + id) = o;
        return;
    }
    {                                          // ---- gemm1 tile (fp32 in) ----
        ushort_t (*as)[64] = (ushort_t(*)[64])smem;
        ushort_t (*bs)[64] = (ushort_t(*)[64])(smem + 8192);
        const int wave = t >> 6, lane = t & 63;
        const int wm = (wave & 1) * 32, wn = (wave >> 1) * 32;
        const int fm = lane & 15, fq = lane >> 4;
        const int idx = b - E_WI;
        const int c0 = (idx % 20) * 64, r0 = (idx / 20) * 64;
        const float* Bsrc = (c0 < 256) ? Wm0 + (size_t)c0 * DD
                          : (c0 < 512) ? Wm1 + (size_t)(c0 - 256) * DD
                                       : whh + (size_t)(c0 - 512) * DD;
        f4 acc[2][2] = {};
        gemm_core_f32(x, DD, Bsrc, DD, r0, 0, DD, as, bs, acc);
        // C/D layout (m89-verified): col = lane&15, row = (lane>>4)*4 + reg
        #pragma unroll
        for (int ni = 0; ni < 2; ++ni) {
            const int col = c0 + wn + ni * 16 + fm;
            const float bv = (col < 256) ? bm0[col]
                           : (col < 512) ? bm1[col - 256]
                                         : bhh[col - 512];
            #pragma unroll
            for (int mi = 0; mi < 2; ++mi) {
                #pragma unroll
                for (int r = 0; r < 4; ++r) {
                    const int row = r0 + wm + mi * 16 + fq * 4 + r;
                    const float v = acc[mi][ni][r] + bv;
                    if (col < 512) msgb[(size_t)row * 512 + col] = f2b(v);
                    else           gh[(size_t)row * 768 + col - 512] = v;
                }
            }
        }
    }
}

// ---------------------------------------------------------------------------
// K2 attn: gather w per edge, edge-only softmax (== dense reference:
// exp(NEG-m) underflows to 0; isolated -> 0 via inv=0), aggregate bf16 msg.
// ---------------------------------------------------------------------------
__global__ __launch_bounds__(256) void attn_kernel(
    const int* __restrict__ cnt, const int* __restrict__ ej,
    const float* __restrict__ w0, const float* __restrict__ w1,
    const float* __restrict__ acur, const float* __restrict__ anb,
    const float* __restrict__ ba0, const float* __restrict__ ba1,
    const ushort_t* __restrict__ msgb, ushort_t* __restrict__ mcatb)
{
    const int i = blockIdx.x, l = blockIdx.y, t = threadIdx.x;
    __shared__ float es[HH][ECAP];
    __shared__ int ejs[ECAP];
    const int ne = min(max(cnt[l * NN + i], 0), ECAP);
    const float* ba = l ? ba1 : ba0;
    const float* w  = l ? w1 : w0;
    const size_t ebase = ((size_t)l * NN + i) * ECAP;

    if (t < ne) {
        const int j = ej[ebase + t];
        const float wv = w[(size_t)j * NN + i];   // latency-parallel gather
        ejs[t] = j;
        const float4 av = *(const float4*)(anb + ((size_t)l * NN + j) * HH);
        const float sv[4] = {av.x, av.y, av.z, av.w};
        #pragma unroll
        for (int h = 0; h < HH; ++h) {
            float s = sv[h] + acur[((size_t)l * NN + i) * HH + h] + ba[h];
            s = (s > 0.f) ? s : 0.2f * s;           // leaky_relu(0.2)
            es[h][t] = s * wv;
        }
    }
    __syncthreads();
    {
        const int h = t >> 6, lane = t & 63;
        float s0 = (lane < ne) ? es[h][lane] : -1e30f;
        float s1 = (lane + 64 < ne) ? es[h][lane + 64] : -1e30f;
        float m = fmaxf(s0, s1);
        #pragma unroll
        for (int off = 32; off; off >>= 1) m = fmaxf(m, __shfl_xor(m, off));
        const float p0 = expf(s0 - m), p1 = expf(s1 - m);
        float sum = p0 + p1;
        #pragma unroll
        for (int off = 32; off; off >>= 1) sum += __shfl_xor(sum, off);
        const float inv = (ne > 0) ? 1.f / sum : 0.f;
        es[h][lane] = p0 * inv;
        if (lane + 64 < ECAP) es[h][lane + 64] = p1 * inv;
    }
    __syncthreads();
    const int h = t >> 6;
    const int off = l * DD + t;
    float acc = 0.f;
    int e = 0;
    for (; e + 4 <= ne; e += 4) {
        const float v0 = b2f(msgb[(size_t)ejs[e + 0] * 512 + off]);
        const float v1 = b2f(msgb[(size_t)ejs[e + 1] * 512 + off]);
        const float v2 = b2f(msgb[(size_t)ejs[e + 2] * 512 + off]);
        const float v3 = b2f(msgb[(size_t)ejs[e + 3] * 512 + off]);
        acc = fmaf(es[h][e + 0], v0, acc);
        acc = fmaf(es[h][e + 1], v1, acc);
        acc = fmaf(es[h][e + 2], v2, acc);
        acc = fmaf(es[h][e + 3], v3, acc);
    }
    for (; e < ne; ++e)
        acc = fmaf(es[h][e], b2f(msgb[(size_t)ejs[e] * 512 + off]), acc);
    mcatb[(size_t)i * (2 * DD) + off] = f2b(acc);
}

// ---------------------------------------------------------------------------
// K3: gemm2: gi[2048,768] = mcatb @ wihb^T + bih   (K=512, bf16 core)
// ---------------------------------------------------------------------------
__global__ __launch_bounds__(256) void gemm2_kernel(
    const ushort_t* __restrict__ mcatb, const ushort_t* __restrict__ wihb,
    const float* __restrict__ bih, float* __restrict__ gi)
{
    __shared__ ushort_t as[64][64];
    __shared__ ushort_t bs[64][64];
    const int t = threadIdx.x;
    const int wave = t >> 6, lane = t & 63;
    const int wm = (wave & 1) * 32, wn = (wave >> 1) * 32;
    const int fm = lane & 15, fq = lane >> 4;
    const int c0 = blockIdx.x * 64, r0 = blockIdx.y * 64;
    f4 acc[2][2] = {};
    gemm_core(mcatb, 512, wihb, 512, r0, c0, 512, as, bs, acc);
    #pragma unroll
    for (int ni = 0; ni < 2; ++ni) {
        const int col = c0 + wn + ni * 16 + fm;
        const float bv = bih[col];
        #pragma unroll
        for (int mi = 0; mi < 2; ++mi)
            #pragma unroll
            for (int r = 0; r < 4; ++r)
                gi[(size_t)(r0 + wm + mi * 16 + fq * 4 + r) * 768 + col] =
                    acc[mi][ni][r] + bv;
    }
}

// ---------------------------------------------------------------------------
// K4: GRU gates + LayerNorm.
// ---------------------------------------------------------------------------
__global__ __launch_bounds__(256) void gates_ln(
    const float* __restrict__ gi, const float* __restrict__ gh, const float* __restrict__ x,
    const float* __restrict__ lng, const float* __restrict__ lnb, float* __restrict__ out)
{
    __shared__ float rs1[4], rs2[4];
    const int t = threadIdx.x;
    const int r0 = blockIdx.x * 4;
    const float gv = lng[t], bv = lnb[t];
    float hv[4];
    #pragma unroll
    for (int r = 0; r < 4; ++r) {
        const int row = r0 + r;
        const float gir = gi[(size_t)row * 768 + t];
        const float giz = gi[(size_t)row * 768 + 256 + t];
        const float gin = gi[(size_t)row * 768 + 512 + t];
        const float ghr = gh[(size_t)row * 768 + t];
        const float ghz = gh[(size_t)row * 768 + 256 + t];
        const float ghn = gh[(size_t)row * 768 + 512 + t];
        const float rr = 1.f / (1.f + expf(-(gir + ghr)));
        const float zz = 1.f / (1.f + expf(-(giz + ghz)));
        const float nn = tanhf(gin + rr * ghn);
        hv[r] = (1.f - zz) * nn + zz * x[(size_t)row * DD + t];
    }
    const int lane = t & 63, wid = t >> 6;
    for (int r = 0; r < 4; ++r) {
        float s1 = hv[r], s2 = hv[r] * hv[r];
        #pragma unroll
        for (int off = 32; off; off >>= 1) {
            s1 += __shfl_down(s1, off);
            s2 += __shfl_down(s2, off);
        }
        if (lane == 0) { rs1[wid] = s1; rs2[wid] = s2; }
        __syncthreads();
        const float sum = rs1[0] + rs1[1] + rs1[2] + rs1[3];
        const float sq  = rs2[0] + rs2[1] + rs2[2] + rs2[3];
        const float mu  = sum * (1.f / DD);
        const float var = sq * (1.f / DD) - mu * mu;
        const float inv = rsqrtf(var + 1e-5f);
        out[(size_t)(r0 + r) * DD + t] = (hv[r] - mu) * inv * gv + bv;
        __syncthreads();
    }
}

extern "C" void kernel_launch(void* const* d_in, const int* in_sizes, int n_in,
                              void* d_out, int out_size, void* d_ws, size_t ws_size,
                              hipStream_t stream)
{
    const float* x    = (const float*)d_in[0];
    const float* adj0 = (const float*)d_in[1];
    const float* adj1 = (const float*)d_in[2];
    const float* w0   = (const float*)d_in[3];
    const float* w1   = (const float*)d_in[4];
    const float* Wm0  = (const float*)d_in[5];
    const float* bm0  = (const float*)d_in[6];
    const float* Wa0  = (const float*)d_in[7];
    const float* ba0  = (const float*)d_in[8];
    const float* Wm1  = (const float*)d_in[9];
    const float* bm1  = (const float*)d_in[10];
    const float* Wa1  = (const float*)d_in[11];
    const float* ba1  = (const float*)d_in[12];
    const float* wih  = (const float*)d_in[13];
    const float* whh  = (const float*)d_in[14];
    const float* bih  = (const float*)d_in[15];
    const float* bhh  = (const float*)d_in[16];
    const float* lng  = (const float*)d_in[17];
    const float* lnb  = (const float*)d_in[18];
    float* out = (float*)d_out;

    float* ws = (float*)d_ws;
    float* gh   = ws;            ws += (size_t)NN * 768;
    float* gi   = ws;            ws += (size_t)NN * 768;
    float* acur = ws;            ws += 2 * NN * HH;
    float* anb  = ws;            ws += 2 * NN * HH;
    int*   cnt  = (int*)ws;      ws += 2 * NN;
    int*   ej   = (int*)ws;      ws += 2 * NN * ECAP;
    ushort_t* wihb  = (ushort_t*)ws;  ws += (size_t)768 * 512 / 2;
    ushort_t* msgb  = (ushort_t*)ws;  ws += (size_t)NN * 512 / 2;
    ushort_t* mcatb = (ushort_t*)ws;  ws += (size_t)NN * 512 / 2;
    // total ~17 MB

    fused1_kernel<<<E_NB, 256, 0, stream>>>(
        x, adj0, adj1, Wm0, Wm1, whh, wih, Wa0, Wa1, bm0, bm1, bhh,
        cnt, ej, wihb, acur, anb, msgb, gh);
    attn_kernel<<<dim3(NN, 2), 256, 0, stream>>>(
        cnt, ej, w0, w1, acur, anb, ba0, ba1, msgb, mcatb);
    gemm2_kernel<<<dim3(12, 32), 256, 0, stream>>>(mcatb, wihb, bih, gi);
    gates_ln<<<NN / 4, 256, 0, stream>>>(gi, gh, x, lng, lnb, out);
}